// Round 9
// baseline (492.204 us; speedup 1.0000x reference)
//
#include <hip/hip_runtime.h>
#include <hip/hip_bf16.h>
#include <stdint.h>

#define BATCH 2048
#define FDIM 512
#define CDIM 64

typedef unsigned short ushort_t;
typedef __attribute__((ext_vector_type(8))) short short8;
typedef __attribute__((ext_vector_type(4))) float f32x4;

__device__ __forceinline__ ushort_t f2bf(float x) {
    union { float f; uint32_t u; } v; v.f = x;
    uint32_t u = v.u;
    uint32_t r = u + 0x7FFFu + ((u >> 16) & 1u);  // round-to-nearest-even
    return (ushort_t)(r >> 16);
}
__device__ __forceinline__ float bf2f(ushort_t u) {
    union { float f; uint32_t v; } x; x.v = ((uint32_t)u) << 16; return x.f;
}

// ---- fused fp32->bf16 convert: one float4 load / ushort4 store per thread ----
// W: 16384 blocks, f: 1024, t: 1024  (each block = 256 float4s)
__global__ void convert_all_kernel(const float* __restrict__ W, ushort_t* __restrict__ Wb,
                                   const float* __restrict__ f, ushort_t* __restrict__ f16,
                                   const float* __restrict__ t, ushort_t* __restrict__ t16) {
    int blk = blockIdx.x;
    const float* src; ushort_t* dst; int idx;
    if (blk < 16384)      { src = W; dst = Wb;  idx = blk * 256 + threadIdx.x; }
    else if (blk < 17408) { src = f; dst = f16; idx = (blk - 16384) * 256 + threadIdx.x; }
    else                  { src = t; dst = t16; idx = (blk - 17408) * 256 + threadIdx.x; }
    float4 v = ((const float4*)src)[idx];
    ushort_t p[4] = { f2bf(v.x), f2bf(v.y), f2bf(v.z), f2bf(v.w) };
    *(ushort4*)&dst[idx * 4] = *(ushort4*)p;
}

#define AS3(p) ((__attribute__((address_space(3))) void*)(p))
#define AS1(p) ((const __attribute__((address_space(1))) void*)(p))

// ---- B-panel-resident barrier-free GEMM ----
// Block owns n-panel of 64 (n = c*512 + i) and ALL m. B panel (64x512 bf16 = 64 KiB)
// staged to LDS ONCE, one __syncthreads, then the main loop has NO barriers and NO
// waitcnt: {A global loads (L2-resident 2 MiB), B ds_reads, MFMA} freely pipelined
// by the compiler. LDS is read-only after the sync -> race-free by construction.
//
// B LDS layout: phys row p holds n_local = ((p&15)<<2)|(p>>4)  (R0-verified permute:
// frag ni reads phys row ni*16+l15 -> D frag ni, col l15 -> n_local = l15*4+ni, so
// the epilogue's 4 t16 factors are one ushort4). Rows = 64 chunks of 16B; phys
// chunk = content chunk ^ (row&7) (both-sides involution: staged source pre-swizzled,
// ds_read XORs) -> 16-lane read phases hit 8 distinct 16B slots (2-way = free).

__launch_bounds__(512, 4)
__global__ void gemm_fused_kernel(const ushort_t* __restrict__ f16,
                                  const ushort_t* __restrict__ Wb,
                                  const ushort_t* __restrict__ t16,
                                  float* __restrict__ part) {
    __shared__ ushort_t Bs[64 * 512];   // 64 KiB -> 2 blocks/CU (128 KiB)

    const int tid  = threadIdx.x;
    const int wave = tid >> 6;      // 0..7 = m-stripe
    const int lane = tid & 63;
    const int l15  = lane & 15;
    const int lg   = lane >> 4;

    const int n0 = blockIdx.x * 64;           // 512 panels cover N = 32768

    // ---- stage B panel once: slot s = l*512+tid -> LDS element s*8 (linear dest);
    //      content: phys row p = s>>6, phys chunk pc = s&63, global chunk = pc^(p&7),
    //      global row = n0 + ((p&15)<<2 | p>>4).
    #pragma unroll
    for (int l = 0; l < 8; l++) {
        int s    = l * 512 + tid;
        int p    = s >> 6;
        int pc   = s & 63;
        int cg   = pc ^ (p & 7);
        int nrot = ((p & 15) << 2) | (p >> 4);
        __builtin_amdgcn_global_load_lds(
            AS1(Wb + (size_t)(n0 + nrot) * FDIM + cg * 8),
            AS3(&Bs[l * 4096 + wave * 512]), 16, 0, 0);
    }
    __syncthreads();   // the ONLY barrier

    // B frag read bases: frag ni reads phys row ni*16+l15; chunk(t) = (t<<2) ^ g
    const int g = lg ^ (l15 & 7);
    int qrow[4];
    #pragma unroll
    for (int ni = 0; ni < 4; ni++) qrow[ni] = (ni * 16 + l15) * FDIM;

    const int c  = n0 >> 9;            // output channel
    const int e8 = (n0 >> 6) & 7;      // i-eighth within channel
    const int ib = (n0 & 511) + l15 * 4;

    // ---- main loop: 4 m-chunks of 64 rows; full K per chunk; no syncs.
    #pragma unroll 1
    for (int mc = 0; mc < 4; mc++) {
        const int m0 = wave * 256 + mc * 64;

        const ushort_t* pA[4];
        #pragma unroll
        for (int mi = 0; mi < 4; mi++)
            pA[mi] = f16 + (size_t)(m0 + mi * 16 + l15) * FDIM + lg * 8;

        f32x4 acc[4][4];
        #pragma unroll
        for (int mi = 0; mi < 4; mi++)
            #pragma unroll
            for (int ni = 0; ni < 4; ni++)
                acc[mi][ni] = (f32x4){0.f, 0.f, 0.f, 0.f};

        #pragma unroll
        for (int t = 0; t < 16; t++) {
            short8 a[4], b[4];
            #pragma unroll
            for (int mi = 0; mi < 4; mi++)
                a[mi] = *(const short8*)(pA[mi] + t * 32);
            #pragma unroll
            for (int ni = 0; ni < 4; ni++)
                b[ni] = *(const short8*)&Bs[qrow[ni] + (((t << 2) ^ g)) * 8];
            #pragma unroll
            for (int mi = 0; mi < 4; mi++)
                #pragma unroll
                for (int ni = 0; ni < 4; ni++)
                    acc[mi][ni] = __builtin_amdgcn_mfma_f32_16x16x32_bf16(
                        a[mi], b[ni], acc[mi][ni], 0, 0, 0);
        }

        // epilogue for this chunk: contract with t16, reduce over l15-group, write.
        #pragma unroll
        for (int mi = 0; mi < 4; mi++) {
            #pragma unroll
            for (int r = 0; r < 4; r++) {
                int b_idx = m0 + mi * 16 + lg * 4 + r;
                ushort4 tv = *(const ushort4*)&t16[(size_t)b_idx * FDIM + ib];
                float sv = acc[mi][0][r] * bf2f(tv.x) + acc[mi][1][r] * bf2f(tv.y)
                         + acc[mi][2][r] * bf2f(tv.z) + acc[mi][3][r] * bf2f(tv.w);
                sv += __shfl_xor(sv, 1, 64);
                sv += __shfl_xor(sv, 2, 64);
                sv += __shfl_xor(sv, 4, 64);
                sv += __shfl_xor(sv, 8, 64);
                if (l15 == 0)
                    part[((size_t)b_idx * CDIM + c) * 8 + e8] = sv;
            }
        }
    }
}

// ---- MLP head: part[b][c][8] eighths -> relu(proj) -> relu(W1) -> W2 ----
__global__ void mlp_kernel(const float* __restrict__ part,
                           const float* __restrict__ b_proj,
                           const float* __restrict__ W1, const float* __restrict__ b1,
                           const float* __restrict__ W2, const float* __restrict__ b2,
                           float* __restrict__ out) {
    __shared__ float h[8][64];
    const int tid = threadIdx.x;
    const int bl  = tid >> 5;        // 0..7
    const int o   = tid & 31;
    const int b   = blockIdx.x * 8 + bl;

    #pragma unroll
    for (int c = o; c < 64; c += 32) {
        const float* pp = &part[(((size_t)b * 64 + c)) * 8];
        float4 v0 = *(const float4*)pp;
        float4 v1 = *(const float4*)(pp + 4);
        float sv = v0.x + v0.y + v0.z + v0.w + v1.x + v1.y + v1.z + v1.w + b_proj[c];
        h[bl][c] = sv > 0.f ? sv : 0.f;
    }
    __syncthreads();

    float sv = b1[o];
    #pragma unroll
    for (int c = 0; c < 64; c++) sv += h[bl][c] * W1[o * 64 + c];
    float v = (sv > 0.f ? sv : 0.f) * W2[o];
    v += __shfl_xor(v, 1, 32);
    v += __shfl_xor(v, 2, 32);
    v += __shfl_xor(v, 4, 32);
    v += __shfl_xor(v, 8, 32);
    v += __shfl_xor(v, 16, 32);
    if (o == 0) out[b] = v + b2[0];
}

extern "C" void kernel_launch(void* const* d_in, const int* in_sizes, int n_in,
                              void* d_out, int out_size, void* d_ws, size_t ws_size,
                              hipStream_t stream) {
    const float* t_feat = (const float*)d_in[0];
    const float* f_feat = (const float*)d_in[1];
    const float* W_proj = (const float*)d_in[2];
    const float* b_proj = (const float*)d_in[3];
    const float* W1     = (const float*)d_in[4];
    const float* b1     = (const float*)d_in[5];
    const float* W2     = (const float*)d_in[6];
    const float* b2     = (const float*)d_in[7];
    float* out = (float*)d_out;

    uint8_t* ws = (uint8_t*)d_ws;
    ushort_t* Wb   = (ushort_t*)(ws);                          // 32 MiB
    ushort_t* f16  = (ushort_t*)(ws + 33554432);               // 2 MiB
    ushort_t* t16  = (ushort_t*)(ws + 33554432 + 2097152);     // 2 MiB
    float*    part = (float*)(ws + 33554432 + 2 * 2097152);    // 4 MiB

    convert_all_kernel<<<dim3(18432), dim3(256), 0, stream>>>(W_proj, Wb, f_feat, f16, t_feat, t16);

    gemm_fused_kernel<<<dim3(512), dim3(512), 0, stream>>>(f16, Wb, t16, part);

    mlp_kernel<<<dim3(BATCH / 8), dim3(256), 0, stream>>>(part, b_proj, W1, b1, W2, b2, out);
}

// Round 10
// 205.366 us; speedup vs baseline: 2.3967x; 2.3967x over previous
//
#include <hip/hip_runtime.h>
#include <hip/hip_bf16.h>
#include <stdint.h>

#define BATCH 2048
#define FDIM 512
#define CDIM 64

typedef unsigned short ushort_t;
typedef __attribute__((ext_vector_type(8))) short short8;
typedef __attribute__((ext_vector_type(4))) float f32x4;

__device__ __forceinline__ ushort_t f2bf(float x) {
    union { float f; uint32_t u; } v; v.f = x;
    uint32_t u = v.u;
    uint32_t r = u + 0x7FFFu + ((u >> 16) & 1u);  // round-to-nearest-even
    return (ushort_t)(r >> 16);
}
__device__ __forceinline__ float bf2f(ushort_t u) {
    union { float f; uint32_t v; } x; x.v = ((uint32_t)u) << 16; return x.f;
}

// ---- fused fp32->bf16 convert: W_proj (8192 blocks), f_feat (512), t_feat (512) ----
__global__ void convert_all_kernel(const float* __restrict__ W, ushort_t* __restrict__ Wb,
                                   const float* __restrict__ f, ushort_t* __restrict__ f16,
                                   const float* __restrict__ t, ushort_t* __restrict__ t16) {
    int blk = blockIdx.x;
    const float* src; ushort_t* dst; int idx;
    if (blk < 8192)      { src = W; dst = Wb;  idx = blk * 256 + threadIdx.x; }
    else if (blk < 8704) { src = f; dst = f16; idx = (blk - 8192) * 256 + threadIdx.x; }
    else                 { src = t; dst = t16; idx = (blk - 8704) * 256 + threadIdx.x; }
    float4 v0 = ((const float4*)src)[idx * 2];
    float4 v1 = ((const float4*)src)[idx * 2 + 1];
    ushort_t p[8] = { f2bf(v0.x), f2bf(v0.y), f2bf(v0.z), f2bf(v0.w),
                      f2bf(v1.x), f2bf(v1.y), f2bf(v1.z), f2bf(v1.w) };
    *(uint4*)&dst[idx * 8] = *(uint4*)p;
}

#define AS3(p) ((__attribute__((address_space(3))) void*)(p))
#define AS1(p) ((const __attribute__((address_space(1))) void*)(p))

// ---- 256x256 tile, BK=32, double-buffered LDS, ONE __syncthreads per K-step ----
// R7's verified race-free schedule (stage t+1 -> compute t -> full __syncthreads),
// tile doubled to halve staged traffic/MFMA: 1 GiB -> 512 MiB global->LDS.
// 16 waves (4x4), each computes 64x64. One global_load_lds per thread per matrix
// per K-step (1024 lanes x 16B = 16KB tile).
// u[b,n] = sum_j f16[b,j]*Wb[n,j]; n = c*512+i; epilogue contracts with t16[b,i].

#define STAGE(bi, kt)                                                               \
    __builtin_amdgcn_global_load_lds(AS1(gA + (kt) * 32), AS3(&As[bi][wave * 512]), 16, 0, 0); \
    __builtin_amdgcn_global_load_lds(AS1(gB + (kt) * 32), AS3(&Bs[bi][wave * 512]), 16, 0, 0);

#define COMPUTE(bi)                                                                 \
    { short8 a[4], b[4];                                                            \
      _Pragma("unroll")                                                             \
      for (int mi = 0; mi < 4; mi++) a[mi] = *(const short8*)&As[bi][a_off[mi]];    \
      _Pragma("unroll")                                                             \
      for (int ni = 0; ni < 4; ni++) b[ni] = *(const short8*)&Bs[bi][b_off[ni]];    \
      _Pragma("unroll")                                                             \
      for (int mi = 0; mi < 4; mi++) {                                              \
        _Pragma("unroll")                                                           \
        for (int ni = 0; ni < 4; ni++)                                              \
          acc[mi][ni] = __builtin_amdgcn_mfma_f32_16x16x32_bf16(                    \
              a[mi], b[ni], acc[mi][ni], 0, 0, 0);                                  \
      } }

__launch_bounds__(1024, 4)
__global__ void gemm_fused_kernel(const ushort_t* __restrict__ f16,
                                  const ushort_t* __restrict__ Wb,
                                  const ushort_t* __restrict__ t16,
                                  float* __restrict__ part) {
    __shared__ ushort_t As[2][256 * 32];   // 2 x 16 KiB
    __shared__ ushort_t Bs[2][256 * 32];   // 2 x 16 KiB
    __shared__ float scratch[256 * 4];     // 68 KiB total

    const int tid  = threadIdx.x;
    const int wave = tid >> 6;      // 0..15
    const int lane = tid & 63;
    const int l15  = lane & 15;
    const int lg   = lane >> 4;
    const int wm   = wave >> 2;     // 0..3 (m quarter, 64 rows)
    const int wn   = wave & 3;      // 0..3 (n quarter, 64 cols)
    const int m_base = wm * 64;
    const int n_base = wn * 64;

    // XCD-chunked bijective swizzle (grid 1024), m fastest within each XCD:
    // each XCD owns 16 consecutive n-panels (B slice 16 x 256 x 1KB = 4 MiB -> L2).
    const int xcd = blockIdx.x & 7;
    const int idx = blockIdx.x >> 3;          // 0..127
    const int bx  = idx & 7;                  // m chunk (fastest), 0..7
    const int by  = xcd * 16 + (idx >> 3);    // n panel 0..127
    const int b0  = bx * 256;
    const int n0  = by * 256;

    // staging: thread tid -> slot s=tid -> LDS element s*8 (row p=s>>2 at p*32,
    // chunk cph=s&3); content chunk cg = cph ^ ((p>>1)&3) (R0-verified swizzle).
    // B row-permute: phys row p holds n_local = (p&192) | ((p&15)<<2) | ((p>>4)&3)
    //   -> frag ni (phys row wn*64+ni*16+l15) yields n_local = wn*64 + l15*4 + ni.
    const int p    = tid >> 2;
    const int cph  = tid & 3;
    const int cg   = cph ^ ((p >> 1) & 3);
    const int nrot = (p & 192) | ((p & 15) << 2) | ((p >> 4) & 3);

    const ushort_t* gA = f16 + (size_t)(b0 + p) * FDIM + cg * 8;
    const ushort_t* gB = Wb + (size_t)(n0 + nrot) * FDIM + cg * 8;

    // fragment ds_read element offsets (within one buffer); chunk XOR = (l15>>1)&3
    int a_off[4], b_off[4];
    #pragma unroll
    for (int mi = 0; mi < 4; mi++)
        a_off[mi] = (m_base + mi * 16 + l15) * 32 + (lg ^ ((l15 >> 1) & 3)) * 8;
    #pragma unroll
    for (int ni = 0; ni < 4; ni++)
        b_off[ni] = (n_base + ni * 16 + l15) * 32 + (lg ^ ((l15 >> 1) & 3)) * 8;

    f32x4 acc[4][4];
    #pragma unroll
    for (int mi = 0; mi < 4; mi++)
        #pragma unroll
        for (int ni = 0; ni < 4; ni++)
            acc[mi][ni] = (f32x4){0.f, 0.f, 0.f, 0.f};

    // pipeline: 16 K-tiles, tile t in buf t%2; stage t+1 at top of step t,
    // compute t, then ONE __syncthreads (drain lands after compute).
    STAGE(0, 0)
    __syncthreads();
    #pragma unroll 1
    for (int t2 = 0; t2 < 7; t2++) {
        const int kt = t2 * 2;
        STAGE(1, kt + 1) COMPUTE(0) __syncthreads();
        STAGE(0, kt + 2) COMPUTE(1) __syncthreads();
    }
    STAGE(1, 15) COMPUTE(0) __syncthreads();
    COMPUTE(1)

    // epilogue: contract with t16. Frag ni, col l15 -> i = (n0&511)+n_base+l15*4+ni;
    // shuffle over l15 sums this wave's 64 i-values; wn quarters summed via scratch.
    const int c    = n0 >> 9;
    const int half = (n0 >> 8) & 1;
    const int i_base = (n0 & 511) + n_base + l15 * 4;

    #pragma unroll
    for (int mi = 0; mi < 4; mi++) {
        #pragma unroll
        for (int r = 0; r < 4; r++) {
            int b_idx = b0 + m_base + mi * 16 + lg * 4 + r;
            ushort4 tv = *(const ushort4*)&t16[(size_t)b_idx * FDIM + i_base];
            float sv = acc[mi][0][r] * bf2f(tv.x) + acc[mi][1][r] * bf2f(tv.y)
                     + acc[mi][2][r] * bf2f(tv.z) + acc[mi][3][r] * bf2f(tv.w);
            sv += __shfl_xor(sv, 1, 64);
            sv += __shfl_xor(sv, 2, 64);
            sv += __shfl_xor(sv, 4, 64);
            sv += __shfl_xor(sv, 8, 64);
            if (l15 == 0)
                scratch[(m_base + mi * 16 + lg * 4 + r) * 4 + wn] = sv;
        }
    }
    __syncthreads();
    if (tid < 256) {
        float4 s4 = *(const float4*)&scratch[tid * 4];
        part[((size_t)(b0 + tid) * CDIM + c) * 2 + half] = s4.x + s4.y + s4.z + s4.w;
    }
}

// ---- MLP head: part[b][c][2] halves -> relu(proj) -> relu(W1) -> W2 ----
__global__ void mlp_kernel(const float* __restrict__ part,
                           const float* __restrict__ b_proj,
                           const float* __restrict__ W1, const float* __restrict__ b1,
                           const float* __restrict__ W2, const float* __restrict__ b2,
                           float* __restrict__ out) {
    __shared__ float h[8][64];
    const int tid = threadIdx.x;
    const int bl  = tid >> 5;        // 0..7
    const int o   = tid & 31;
    const int b   = blockIdx.x * 8 + bl;

    #pragma unroll
    for (int c = o; c < 64; c += 32) {
        float2 v = *(const float2*)&part[((size_t)b * 64 + c) * 2];
        float sv = v.x + v.y + b_proj[c];
        h[bl][c] = sv > 0.f ? sv : 0.f;
    }
    __syncthreads();

    float sv = b1[o];
    #pragma unroll
    for (int c = 0; c < 64; c++) sv += h[bl][c] * W1[o * 64 + c];
    float v = (sv > 0.f ? sv : 0.f) * W2[o];
    v += __shfl_xor(v, 1, 32);
    v += __shfl_xor(v, 2, 32);
    v += __shfl_xor(v, 4, 32);
    v += __shfl_xor(v, 8, 32);
    v += __shfl_xor(v, 16, 32);
    if (o == 0) out[b] = v + b2[0];
}

extern "C" void kernel_launch(void* const* d_in, const int* in_sizes, int n_in,
                              void* d_out, int out_size, void* d_ws, size_t ws_size,
                              hipStream_t stream) {
    const float* t_feat = (const float*)d_in[0];
    const float* f_feat = (const float*)d_in[1];
    const float* W_proj = (const float*)d_in[2];
    const float* b_proj = (const float*)d_in[3];
    const float* W1     = (const float*)d_in[4];
    const float* b1     = (const float*)d_in[5];
    const float* W2     = (const float*)d_in[6];
    const float* b2     = (const float*)d_in[7];
    float* out = (float*)d_out;

    uint8_t* ws = (uint8_t*)d_ws;
    ushort_t* Wb   = (ushort_t*)(ws);                          // 32 MiB
    ushort_t* f16  = (ushort_t*)(ws + 33554432);               // 2 MiB
    ushort_t* t16  = (ushort_t*)(ws + 33554432 + 2097152);     // 2 MiB
    float*    part = (float*)(ws + 33554432 + 2 * 2097152);    // 1 MiB

    convert_all_kernel<<<dim3(9216), dim3(256), 0, stream>>>(W_proj, Wb, f_feat, f16, t_feat, t16);

    gemm_fused_kernel<<<dim3(1024), dim3(1024), 0, stream>>>(f16, Wb, t16, part);

    mlp_kernel<<<dim3(BATCH / 8), dim3(256), 0, stream>>>(part, b_proj, W1, b1, W2, b2, out);
}

// Round 11
// 202.951 us; speedup vs baseline: 2.4252x; 1.0119x over previous
//
#include <hip/hip_runtime.h>
#include <hip/hip_bf16.h>
#include <stdint.h>

#define BATCH 2048
#define FDIM 512
#define CDIM 64

typedef unsigned short ushort_t;
typedef __attribute__((ext_vector_type(8))) short short8;
typedef __attribute__((ext_vector_type(4))) float f32x4;

__device__ __forceinline__ ushort_t f2bf(float x) {
    union { float f; uint32_t u; } v; v.f = x;
    uint32_t u = v.u;
    uint32_t r = u + 0x7FFFu + ((u >> 16) & 1u);  // round-to-nearest-even
    return (ushort_t)(r >> 16);
}
__device__ __forceinline__ float bf2f(ushort_t u) {
    union { float f; uint32_t v; } x; x.v = ((uint32_t)u) << 16; return x.f;
}

// ---- fused fp32->bf16 convert: W_proj (8192 blocks), f_feat (512), t_feat (512) ----
// W-region blocks are XCD-PLACED: the blocks that produce Wb rows [g*4096,(g+1)*4096)
// (the 16 n-panels gemm's XCD g consumes, 4 MiB = one L2) dispatch with blockIdx%8==g,
// so the write-back leaves those lines resident in the CONSUMING XCD's L2. Within an
// XCD the order is reversed so the panels gemm's first generation reads (by 0..7)
// are written LAST (survive convert's own streaming reads). Pure index permutation.
__global__ void convert_all_kernel(const float* __restrict__ W, ushort_t* __restrict__ Wb,
                                   const float* __restrict__ f, ushort_t* __restrict__ f16,
                                   const float* __restrict__ t, ushort_t* __restrict__ t16) {
    int blk = blockIdx.x;
    const float* src; ushort_t* dst; int idx;
    if (blk < 8192) {
        int g  = blk & 7;                 // dispatch XCD (round-robin assumption, m09)
        int j  = blk >> 3;                // 0..1023 within XCD, ascending in time
        int nb = g * 1024 + (1023 - j);   // late blocks write low rows (gen-1 panels)
        src = W; dst = Wb;  idx = nb * 256 + threadIdx.x;
    }
    else if (blk < 8704) { src = f; dst = f16; idx = (blk - 8192) * 256 + threadIdx.x; }
    else                 { src = t; dst = t16; idx = (blk - 8704) * 256 + threadIdx.x; }
    float4 v0 = ((const float4*)src)[idx * 2];
    float4 v1 = ((const float4*)src)[idx * 2 + 1];
    ushort_t p[8] = { f2bf(v0.x), f2bf(v0.y), f2bf(v0.z), f2bf(v0.w),
                      f2bf(v1.x), f2bf(v1.y), f2bf(v1.z), f2bf(v1.w) };
    *(uint4*)&dst[idx * 8] = *(uint4*)p;
}

#define AS3(p) ((__attribute__((address_space(3))) void*)(p))
#define AS1(p) ((const __attribute__((address_space(1))) void*)(p))

// ---- 256x256 tile, BK=32, double-buffered LDS, ONE __syncthreads per K-step ----
// (R10 verbatim — hardware-verified at 96.9 us.)
// u[b,n] = sum_j f16[b,j]*Wb[n,j]; n = c*512+i; epilogue contracts with t16[b,i].

#define STAGE(bi, kt)                                                               \
    __builtin_amdgcn_global_load_lds(AS1(gA + (kt) * 32), AS3(&As[bi][wave * 512]), 16, 0, 0); \
    __builtin_amdgcn_global_load_lds(AS1(gB + (kt) * 32), AS3(&Bs[bi][wave * 512]), 16, 0, 0);

#define COMPUTE(bi)                                                                 \
    { short8 a[4], b[4];                                                            \
      _Pragma("unroll")                                                             \
      for (int mi = 0; mi < 4; mi++) a[mi] = *(const short8*)&As[bi][a_off[mi]];    \
      _Pragma("unroll")                                                             \
      for (int ni = 0; ni < 4; ni++) b[ni] = *(const short8*)&Bs[bi][b_off[ni]];    \
      _Pragma("unroll")                                                             \
      for (int mi = 0; mi < 4; mi++) {                                              \
        _Pragma("unroll")                                                           \
        for (int ni = 0; ni < 4; ni++)                                              \
          acc[mi][ni] = __builtin_amdgcn_mfma_f32_16x16x32_bf16(                    \
              a[mi], b[ni], acc[mi][ni], 0, 0, 0);                                  \
      } }

__launch_bounds__(1024, 4)
__global__ void gemm_fused_kernel(const ushort_t* __restrict__ f16,
                                  const ushort_t* __restrict__ Wb,
                                  const ushort_t* __restrict__ t16,
                                  float* __restrict__ part) {
    __shared__ ushort_t As[2][256 * 32];   // 2 x 16 KiB
    __shared__ ushort_t Bs[2][256 * 32];   // 2 x 16 KiB
    __shared__ float scratch[256 * 4];     // 68 KiB total

    const int tid  = threadIdx.x;
    const int wave = tid >> 6;      // 0..15
    const int lane = tid & 63;
    const int l15  = lane & 15;
    const int lg   = lane >> 4;
    const int wm   = wave >> 2;     // 0..3 (m quarter, 64 rows)
    const int wn   = wave & 3;      // 0..3 (n quarter, 64 cols)
    const int m_base = wm * 64;
    const int n_base = wn * 64;

    // XCD-chunked bijective swizzle (grid 1024), m fastest within each XCD:
    // each XCD owns 16 consecutive n-panels (B slice 4 MiB -> its private L2,
    // pre-warmed by the convert kernel's matching placement).
    const int xcd = blockIdx.x & 7;
    const int idx = blockIdx.x >> 3;          // 0..127
    const int bx  = idx & 7;                  // m chunk (fastest), 0..7
    const int by  = xcd * 16 + (idx >> 3);    // n panel 0..127
    const int b0  = bx * 256;
    const int n0  = by * 256;

    // staging: thread tid -> slot s=tid -> LDS element s*8 (row p=s>>2 at p*32,
    // chunk cph=s&3); content chunk cg = cph ^ ((p>>1)&3) (R0-verified swizzle).
    // B row-permute: phys row p holds n_local = (p&192) | ((p&15)<<2) | ((p>>4)&3)
    //   -> frag ni (phys row wn*64+ni*16+l15) yields n_local = wn*64 + l15*4 + ni.
    const int p    = tid >> 2;
    const int cph  = tid & 3;
    const int cg   = cph ^ ((p >> 1) & 3);
    const int nrot = (p & 192) | ((p & 15) << 2) | ((p >> 4) & 3);

    const ushort_t* gA = f16 + (size_t)(b0 + p) * FDIM + cg * 8;
    const ushort_t* gB = Wb + (size_t)(n0 + nrot) * FDIM + cg * 8;

    // fragment ds_read element offsets (within one buffer); chunk XOR = (l15>>1)&3
    int a_off[4], b_off[4];
    #pragma unroll
    for (int mi = 0; mi < 4; mi++)
        a_off[mi] = (m_base + mi * 16 + l15) * 32 + (lg ^ ((l15 >> 1) & 3)) * 8;
    #pragma unroll
    for (int ni = 0; ni < 4; ni++)
        b_off[ni] = (n_base + ni * 16 + l15) * 32 + (lg ^ ((l15 >> 1) & 3)) * 8;

    f32x4 acc[4][4];
    #pragma unroll
    for (int mi = 0; mi < 4; mi++)
        #pragma unroll
        for (int ni = 0; ni < 4; ni++)
            acc[mi][ni] = (f32x4){0.f, 0.f, 0.f, 0.f};

    // pipeline: 16 K-tiles, tile t in buf t%2; stage t+1 at top of step t,
    // compute t, then ONE __syncthreads (drain lands after compute).
    STAGE(0, 0)
    __syncthreads();
    #pragma unroll 1
    for (int t2 = 0; t2 < 7; t2++) {
        const int kt = t2 * 2;
        STAGE(1, kt + 1) COMPUTE(0) __syncthreads();
        STAGE(0, kt + 2) COMPUTE(1) __syncthreads();
    }
    STAGE(1, 15) COMPUTE(0) __syncthreads();
    COMPUTE(1)

    // epilogue: contract with t16. Frag ni, col l15 -> i = (n0&511)+n_base+l15*4+ni;
    // shuffle over l15 sums this wave's 64 i-values; wn quarters summed via scratch.
    const int c    = n0 >> 9;
    const int half = (n0 >> 8) & 1;
    const int i_base = (n0 & 511) + n_base + l15 * 4;

    #pragma unroll
    for (int mi = 0; mi < 4; mi++) {
        #pragma unroll
        for (int r = 0; r < 4; r++) {
            int b_idx = b0 + m_base + mi * 16 + lg * 4 + r;
            ushort4 tv = *(const ushort4*)&t16[(size_t)b_idx * FDIM + i_base];
            float sv = acc[mi][0][r] * bf2f(tv.x) + acc[mi][1][r] * bf2f(tv.y)
                     + acc[mi][2][r] * bf2f(tv.z) + acc[mi][3][r] * bf2f(tv.w);
            sv += __shfl_xor(sv, 1, 64);
            sv += __shfl_xor(sv, 2, 64);
            sv += __shfl_xor(sv, 4, 64);
            sv += __shfl_xor(sv, 8, 64);
            if (l15 == 0)
                scratch[(m_base + mi * 16 + lg * 4 + r) * 4 + wn] = sv;
        }
    }
    __syncthreads();
    if (tid < 256) {
        float4 s4 = *(const float4*)&scratch[tid * 4];
        part[((size_t)(b0 + tid) * CDIM + c) * 2 + half] = s4.x + s4.y + s4.z + s4.w;
    }
}

// ---- MLP head: part[b][c][2] halves -> relu(proj) -> relu(W1) -> W2 ----
__global__ void mlp_kernel(const float* __restrict__ part,
                           const float* __restrict__ b_proj,
                           const float* __restrict__ W1, const float* __restrict__ b1,
                           const float* __restrict__ W2, const float* __restrict__ b2,
                           float* __restrict__ out) {
    __shared__ float h[8][64];
    const int tid = threadIdx.x;
    const int bl  = tid >> 5;        // 0..7
    const int o   = tid & 31;
    const int b   = blockIdx.x * 8 + bl;

    #pragma unroll
    for (int c = o; c < 64; c += 32) {
        float2 v = *(const float2*)&part[((size_t)b * 64 + c) * 2];
        float sv = v.x + v.y + b_proj[c];
        h[bl][c] = sv > 0.f ? sv : 0.f;
    }
    __syncthreads();

    float sv = b1[o];
    #pragma unroll
    for (int c = 0; c < 64; c++) sv += h[bl][c] * W1[o * 64 + c];
    float v = (sv > 0.f ? sv : 0.f) * W2[o];
    v += __shfl_xor(v, 1, 32);
    v += __shfl_xor(v, 2, 32);
    v += __shfl_xor(v, 4, 32);
    v += __shfl_xor(v, 8, 32);
    v += __shfl_xor(v, 16, 32);
    if (o == 0) out[b] = v + b2[0];
}

extern "C" void kernel_launch(void* const* d_in, const int* in_sizes, int n_in,
                              void* d_out, int out_size, void* d_ws, size_t ws_size,
                              hipStream_t stream) {
    const float* t_feat = (const float*)d_in[0];
    const float* f_feat = (const float*)d_in[1];
    const float* W_proj = (const float*)d_in[2];
    const float* b_proj = (const float*)d_in[3];
    const float* W1     = (const float*)d_in[4];
    const float* b1     = (const float*)d_in[5];
    const float* W2     = (const float*)d_in[6];
    const float* b2     = (const float*)d_in[7];
    float* out = (float*)d_out;

    uint8_t* ws = (uint8_t*)d_ws;
    ushort_t* Wb   = (ushort_t*)(ws);                          // 32 MiB
    ushort_t* f16  = (ushort_t*)(ws + 33554432);               // 2 MiB
    ushort_t* t16  = (ushort_t*)(ws + 33554432 + 2097152);     // 2 MiB
    float*    part = (float*)(ws + 33554432 + 2 * 2097152);    // 1 MiB

    convert_all_kernel<<<dim3(9216), dim3(256), 0, stream>>>(W_proj, Wb, f_feat, f16, t_feat, t16);

    gemm_fused_kernel<<<dim3(1024), dim3(1024), 0, stream>>>(f16, Wb, t16, part);

    mlp_kernel<<<dim3(BATCH / 8), dim3(256), 0, stream>>>(part, b_proj, W1, b1, W2, b2, out);
}